// Round 4
// baseline (16.461 us; speedup 1.0000x reference)
//
#include <hip/hip_runtime.h>

// B=25, N=16, S=5, C=25 (S,N,C hardcoded; B from in_sizes).
// out[k] = (1/B)*sum_b dis_loss[b,k] + (1/(B*C))*sum_{b,c} p_loss[b,c]
//   (the reference's (B,C)+(B,C,1) broadcast + two means, valid since B==C)
// all_match[b,c] == (counts[b,c]==N) == (every point of batch b has label c).
//
// Latency-floor design, round 3:
//  - truth int2 loads issued FIRST (they gate the longest dependent chain)
//  - pred staged to LDS as float4 (2 loads/thread) — off critical path
//  - barrier #1
//  - all_match computed redundantly per-wave (pad-17 rows: conflict-free),
//    p_loss distributed over all 4 waves (3 iters each), shuffle broadcast
//    of amc/txl/tyl stays intra-wave
//  - barrier #2, 25 threads combine + store

#define NT 256

__global__ __launch_bounds__(NT) void loss_26405458936156_kernel(
    const float* __restrict__ pred,   // (B, 75) fp32
    const int*   __restrict__ truth,  // (B, 16, 2) int32
    float*       __restrict__ out,    // (25,)
    int B)
{
    const float cell  = 16.0f;     // 80/S, exact
    const float cellr = 0.0625f;   // S/80, exact (2^-4)

    __shared__ float4 s_pred4[480];          // >= B*75/4 floats (B<=25 -> 469)
    __shared__ int    s_lab[32][17];         // pad 17: conflict-free column reads
    __shared__ float  s_dis[32][17];
    __shared__ float  s_txl[32], s_tyl[32];
    __shared__ float  s_wsum[4];
    float* s_pred = (float*)s_pred4;

    const int t    = threadIdx.x;
    const int lane = t & 63;

    // --- issue truth loads first (critical chain: truth -> label -> gather) ---
    const int2* tr = (const int2*)truth;
    const int   TN = B * 16;
    int2 tv0, tv1;
    const bool h0 = t < TN;
    const bool h1 = t + NT < TN;
    if (h0) tv0 = tr[t];
    if (h1) tv1 = tr[t + NT];

    // --- stage pred -> LDS as float4 (overlaps the truth-dependent phase) ---
    const int PN = B * 75;
    const int n4 = PN >> 2;                  // full float4 slots
    const float4* pr4 = (const float4*)pred;
    for (int s = t; s < n4; s += NT) s_pred4[s] = pr4[s];
    if (t < PN - (n4 << 2)) s_pred[(n4 << 2) + t] = pred[(n4 << 2) + t];

    // --- phase A: truth transform + dis_loss gather (pred lines L1/MSHR-warm) ---
    #pragma unroll
    for (int u = 0; u < 2; ++u) {
        const bool h = u ? h1 : h0;
        if (!h) continue;
        const int  i  = u ? t + NT : t;
        const int2 tv = u ? tv1 : tv0;
        int b = i >> 4, n = i & 15;
        float t0 = (float)tv.x + 14.0f;          // integer-valued, [14,80)
        float t1 = (float)tv.y + 14.0f;
        float fx = floorf(t0 * cellr);           // exact
        float fy = floorf(t1 * cellr);
        float tx = (t0 - fx * cell) * cellr;     // == fmod(t0,cell)*S/80, exact
        float ty = (t1 - fy * cell) * cellr;
        int   lb = (int)fx * 5 + (int)fy;
        s_lab[b][n] = lb;
        if (n == 15) { s_txl[b] = tx * 16.0f; s_tyl[b] = ty * 16.0f; }
        float px = pred[b * 75 + 3 * lb + 1];
        float py = pred[b * 75 + 3 * lb + 2];
        float ex = px - tx, ey = py - ty;
        s_dis[b][n] = 5.0f * (ex * ex + ey * ey);
    }
    __syncthreads();

    // --- all_match redundantly per wave (lane l owns batch l) ---
    int   amc = -1;
    float txl = 0.0f, tyl = 0.0f;
    if (lane < B) {
        int l0 = s_lab[lane][0], all = 1;
        #pragma unroll
        for (int n = 1; n < 16; ++n) all &= (s_lab[lane][n] == l0);
        amc = all ? l0 : -1;
        txl = s_txl[lane];
        tyl = s_tyl[lane];
    }

    // --- p_loss distributed over all waves (B*25 = 625 -> 3 iters/thread) ---
    float psum = 0.0f;
    for (int i = t; i < B * 25; i += NT) {
        int b = i / 25, c = i - b * 25;
        const float* pc = &s_pred[b * 75 + 3 * c];
        float conf = pc[0], cx = pc[1], cy = pc[2];
        int   amcb = __shfl(amc, b);             // intra-wave broadcast
        float txlb = __shfl(txl, b);
        float tylb = __shfl(tyl, b);
        float dx = fabsf(cx * 16.0f - txlb);
        float dy = fabsf(cy * 16.0f - tylb);
        float iou = fmaxf(28.0f - 2.0f * dx, 0.0f) * fmaxf(28.0f - 2.0f * dy, 0.0f)
                  / ((28.0f + dx) * (28.0f + dy));
        float e = conf - iou;
        psum += (amcb == c) ? e * e : 0.5f * conf * conf;
    }
    #pragma unroll
    for (int o = 32; o; o >>= 1) psum += __shfl_xor(psum, o);
    if (lane == 0) s_wsum[t >> 6] = psum;
    __syncthreads();

    // --- combine + store: thread k < 25 writes out[k] ---
    if (t < 25) {
        float P = (s_wsum[0] + s_wsum[1] + s_wsum[2] + s_wsum[3])
                  * (1.0f / (float)(B * 25));
        float acc = 0.0f;
        if (t < 16) {
            for (int b = 0; b < B; ++b) acc += s_dis[b][t];   // pad-17: conflict-free
            acc *= 1.0f / (float)B;
        }
        out[t] = acc + P;
    }
}

extern "C" void kernel_launch(void* const* d_in, const int* in_sizes, int n_in,
                              void* d_out, int out_size, void* d_ws, size_t ws_size,
                              hipStream_t stream) {
    const float* pred  = (const float*)d_in[0];
    const int*   truth = (const int*)d_in[1];
    float*       out   = (float*)d_out;

    const int B = in_sizes[0] / 75;   // pred is (B, 3*S*S), S=5

    loss_26405458936156_kernel<<<1, NT, 0, stream>>>(pred, truth, out, B);
}

// Round 5
// 9.553 us; speedup vs baseline: 1.7231x; 1.7231x over previous
//
#include <hip/hip_runtime.h>

// B=25, N=16, S=5, C=25 (S,N,C hardcoded — fixed by the problem; B runtime).
// out[k] = (1/B)*sum_b dis_loss[b,k] + (1/(B*C))*sum_{b,c} p_loss[b,c]
//   (the reference's (B,C)+(B,C,1) broadcast followed by two means, B==C)
// all_match[b,c] == (counts[b,c]==N) == (every point of batch b has label c).
//
// Latency-floor design: ONE __syncthreads total.
//   cycle 0:  issue pred->LDS staging (also warms L1 for the gather) + truth loads
//   phase A+C fused per (b,n): transform truth (exact fp32: inputs integer-valued,
//             cell=16=2^4), write labels, gather pred from L1, write dis to LDS
//   barrier
//   wave 0:   all_match (pad-17 LDS rows, conflict-free), 625-item p_loss loop
//             with __shfl operand broadcast, 64-lane shuffle reduce, store.
//
// NOTE (round 4): exact re-submission of the round-2 artifact that measured
// 9.37 us — A/A variance test after round 3's unexplained +76%.

#define NT 256

__global__ __launch_bounds__(NT) void loss_26405458936156_kernel(
    const float* __restrict__ pred,   // (B, 75)
    const int*   __restrict__ truth,  // (B, 16, 2) int32
    float*       __restrict__ out,    // (25,)
    int B)
{
    const float cell  = 16.0f;     // 80/S, exact
    const float cellr = 0.0625f;   // S/80, exact (2^-4)

    __shared__ float s_pred[64 * 75];
    __shared__ int   s_lab[64][17];   // pad 17: all-match reads conflict-free
    __shared__ float s_dis[64][17];
    __shared__ float s_txl[64], s_tyl[64];

    const int t = threadIdx.x;

    // Stage pred -> LDS (issued first; overlaps the truth-dependent phase,
    // and pulls every pred line through L1 for the gather below).
    const int PN = B * 75;
    for (int i = t; i < PN; i += NT) s_pred[i] = pred[i];

    // Phase A+C fused: per-(b,n) truth transform + dis_loss gather.
    const int2* tr = (const int2*)truth;   // (x,y) pairs, 8B aligned
    for (int i = t; i < B * 16; i += NT) {
        int b = i >> 4, n = i & 15;
        int2 tv = tr[i];
        float t0 = (float)tv.x + 14.0f;          // integer-valued, [14,80)
        float t1 = (float)tv.y + 14.0f;
        float fx = floorf(t0 * cellr);           // exact
        float fy = floorf(t1 * cellr);
        float tx = (t0 - fx * cell) * cellr;     // == fmod(t0,cell)*S/80, exact
        float ty = (t1 - fy * cell) * cellr;
        int   lb = (int)fx * 5 + (int)fy;
        s_lab[b][n] = lb;
        if (n == 15) { s_txl[b] = tx * 16.0f; s_tyl[b] = ty * 16.0f; }
        // gather own dis_loss term (pred lines L1-resident from staging loads)
        float px = pred[b * 75 + 3 * lb + 1];
        float py = pred[b * 75 + 3 * lb + 2];
        float ex = px - tx, ey = py - ty;
        s_dis[b][n] = 5.0f * (ex * ex + ey * ey);
    }
    __syncthreads();

    // Wave 0 finishes everything — no further barriers.
    if (t < 64) {
        // all_match + last-point coords, one batch per lane
        int   amc = -1;
        float txl = 0.0f, tyl = 0.0f;
        if (t < B) {
            int l0 = s_lab[t][0], all = 1;
            #pragma unroll
            for (int n = 1; n < 16; ++n) all &= (s_lab[t][n] == l0);
            amc = all ? l0 : -1;
            txl = s_txl[t];
            tyl = s_tyl[t];
        }

        // p_loss over all (b,c): operands broadcast via shuffles (no LDS round-trip)
        float psum = 0.0f;
        for (int i = t; i < B * 25; i += 64) {
            int b = i / 25, c = i - b * 25;
            const float* pc = &s_pred[b * 75 + 3 * c];
            float conf = pc[0], cx = pc[1], cy = pc[2];
            int   amcb = __shfl(amc, b);
            float txlb = __shfl(txl, b);
            float tylb = __shfl(tyl, b);
            float dx = fabsf(cx * 16.0f - txlb);
            float dy = fabsf(cy * 16.0f - tylb);
            float iou = fmaxf(28.0f - 2.0f * dx, 0.0f) * fmaxf(28.0f - 2.0f * dy, 0.0f)
                      / ((28.0f + dx) * (28.0f + dy));
            float e = conf - iou;
            psum += (amcb == c) ? e * e : 0.5f * conf * conf;
        }
        // 64-lane butterfly reduce
        #pragma unroll
        for (int o = 32; o; o >>= 1) psum += __shfl_xor(psum, o);

        if (t < 25) {
            float P = psum * (1.0f / (float)(B * 25));
            float acc = 0.0f;
            if (t < 16) {
                for (int b = 0; b < B; ++b) acc += s_dis[b][t];
                acc *= 1.0f / (float)B;
            }
            out[t] = acc + P;
        }
    }
}

extern "C" void kernel_launch(void* const* d_in, const int* in_sizes, int n_in,
                              void* d_out, int out_size, void* d_ws, size_t ws_size,
                              hipStream_t stream) {
    const float* pred  = (const float*)d_in[0];
    const int*   truth = (const int*)d_in[1];
    float*       out   = (float*)d_out;

    const int B = in_sizes[0] / 75;   // pred is (B, 3*S*S), S=5

    loss_26405458936156_kernel<<<1, NT, 0, stream>>>(pred, truth, out, B);
}